// Round 3
// baseline (253.104 us; speedup 1.0000x reference)
//
#include <hip/hip_runtime.h>
#include <hip/hip_bf16.h>

typedef __bf16 bf16;
typedef __attribute__((ext_vector_type(8))) __bf16 bf16x8;
typedef __attribute__((ext_vector_type(4))) float f32x4;

#define MFMA16(A, B, C) __builtin_amdgcn_mfma_f32_16x16x32_bf16((A), (B), (C), 0, 0, 0)

__device__ __forceinline__ void gload_lds16(const void* g, void* l) {
    __builtin_amdgcn_global_load_lds(
        (const __attribute__((address_space(1))) void*)g,
        (__attribute__((address_space(3))) void*)l,
        16, 0, 0);
}

// fp32 -> bf16 cast, 8 elements/thread, exact grid (n % 2048 == 0).
__global__ __launch_bounds__(256) void cast_f32_bf16(
    const float* __restrict__ in, bf16* __restrict__ out)
{
    const int i = (blockIdx.x * 256 + threadIdx.x) * 8;
    const float4 a = *(const float4*)(in + i);
    const float4 b = *(const float4*)(in + i + 4);
    bf16x8 o;
    o[0] = (bf16)a.x; o[1] = (bf16)a.y; o[2] = (bf16)a.z; o[3] = (bf16)a.w;
    o[4] = (bf16)b.x; o[5] = (bf16)b.y; o[6] = (bf16)b.z; o[7] = (bf16)b.w;
    *(bf16x8*)(out + i) = o;
}

// C[M,N] = A[M,K] * B[N,K]^T, bf16 inputs, fp32 accumulate, OutT output.
template <typename OutT>
__global__ __launch_bounds__(256) void gemm_bt128(
    const bf16* __restrict__ A, const bf16* __restrict__ B, OutT* __restrict__ C,
    int M, int N, int K)
{
    constexpr int BK = 32;
    __shared__ __align__(16) bf16 sA[128 * BK];
    __shared__ __align__(16) bf16 sB[128 * BK];

    const int tid  = threadIdx.x;
    const int lane = tid & 63;
    const int wave = tid >> 6;
    const int wr   = wave >> 1;   // 0..1
    const int wc   = wave & 1;    // 0..1
    const int bm   = blockIdx.y * 128;
    const int bn   = blockIdx.x * 128;

    f32x4 acc[4][4] = {};

    const size_t ldb = (size_t)K * 2;  // row stride in bytes
    const int srow = wave * 32 + (lane >> 2);
    const int scol = (lane & 3) * 16;
    const char* Ab = (const char*)A + (size_t)(bm + srow) * ldb + scol;
    const char* Bb = (const char*)B + (size_t)(bn + srow) * ldb + scol;
    char* ldsA = (char*)sA + wave * 2048;
    char* ldsB = (char*)sB + wave * 2048;

    const int arow = wr * 64 + (lane & 15);
    const int brow = wc * 64 + (lane & 15);
    const int koff = (lane >> 4) * 8;

    for (int k0 = 0; k0 < K; k0 += BK) {
        __syncthreads();
        const size_t kb = (size_t)k0 * 2;
        gload_lds16(Ab + kb,                ldsA);
        gload_lds16(Ab + kb + 16 * ldb,     ldsA + 1024);
        gload_lds16(Bb + kb,                ldsB);
        gload_lds16(Bb + kb + 16 * ldb,     ldsB + 1024);
        __syncthreads();

        bf16x8 af[4], bfr[4];
#pragma unroll
        for (int m = 0; m < 4; ++m)
            af[m] = *(const bf16x8*)&sA[(arow + m * 16) * BK + koff];
#pragma unroll
        for (int n = 0; n < 4; ++n)
            bfr[n] = *(const bf16x8*)&sB[(brow + n * 16) * BK + koff];
#pragma unroll
        for (int m = 0; m < 4; ++m)
#pragma unroll
            for (int n = 0; n < 4; ++n)
                acc[m][n] = MFMA16(af[m], bfr[n], acc[m][n]);
    }

    // epilogue: C/D layout col = lane&15, row = (lane>>4)*4 + j  [m89-verified]
    const int crow0 = bm + wr * 64 + (lane >> 4) * 4;
    const int ccol0 = bn + wc * 64 + (lane & 15);
#pragma unroll
    for (int m = 0; m < 4; ++m)
#pragma unroll
        for (int n = 0; n < 4; ++n)
#pragma unroll
            for (int j = 0; j < 4; ++j)
                C[(size_t)(crow0 + m * 16 + j) * N + ccol0 + n * 16] = (OutT)acc[m][n][j];
}

// Flash attention over qkv buffer [B*T, 3072]; writes y [B*T, 1024] (bf16).
// Grid: (T/64, B*H). Block 256 = 4 waves; each wave owns 16 q-rows.
__global__ __launch_bounds__(256) void attn64(
    const bf16* __restrict__ qkv, bf16* __restrict__ y)
{
    constexpr int T = 2048, Cd = 1024, F = 3072, D = 64, KV = 64;
    __shared__ __align__(16) bf16 sK[KV * D];      // linear, XOR-swizzled contents
    __shared__ __align__(16) bf16 sVT[D * 72];     // V transposed, padded stride 72
    __shared__ __align__(16) bf16 sP[4 * 16 * 72]; // per-wave P tiles, stride 72

    const int tid  = threadIdx.x;
    const int lane = tid & 63;
    const int wave = tid >> 6;
    const int bh = blockIdx.y;
    const int b  = bh >> 4, h = bh & 15;
    const int q0 = blockIdx.x * 64;

    const bf16* qkvb = qkv + (size_t)b * T * F;
    const int qcol = h * D;
    const int kcol = Cd + h * D;
    const int vcol = 2 * Cd + h * D;

    // Q fragments (A operand): row = lane&15, k = 8*(lane>>4)+j, contiguous
    const int qrow = q0 + wave * 16 + (lane & 15);
    bf16x8 qf[2];
#pragma unroll
    for (int kk = 0; kk < 2; ++kk)
        qf[kk] = *(const bf16x8*)(qkvb + (size_t)qrow * F + qcol + kk * 32 + (lane >> 4) * 8);

    f32x4 oacc[4] = {};
    float m_r[4] = {-1e30f, -1e30f, -1e30f, -1e30f};
    float l_r[4] = {};

    // K staging: chunk c = wave*2 + r covers rows c*8 + lane/8; swizzle byte^=(row&7)<<4
    const int ksrow  = wave * 16 + (lane >> 3);
    const int kdbyte = 16 * ((lane & 7) ^ (lane >> 3));
    bf16* sPw = sP + wave * 16 * 72;

    for (int s0 = 0; s0 < T; s0 += KV) {
        __syncthreads();
        // stage K (linear LDS dest, pre-swizzled global source)
        gload_lds16((const char*)qkvb + ((size_t)(s0 + ksrow) * F + kcol) * 2 + kdbyte,
                    (char*)sK + wave * 2048);
        gload_lds16((const char*)qkvb + ((size_t)(s0 + ksrow + 8) * F + kcol) * 2 + kdbyte,
                    (char*)sK + wave * 2048 + 1024);
        // stage V transposed (manual)
#pragma unroll
        for (int r = 0; r < 2; ++r) {
            const int d0 = wave * 8 + r * 32;
            bf16x8 v = *(const bf16x8*)(qkvb + (size_t)(s0 + lane) * F + vcol + d0);
#pragma unroll
            for (int i = 0; i < 8; ++i) sVT[(d0 + i) * 72 + lane] = v[i];
        }
        __syncthreads();

        // S = Q K^T (A=Q, B=K rows as [N][K])
        f32x4 sacc[4] = {};
#pragma unroll
        for (int kk = 0; kk < 2; ++kk) {
#pragma unroll
            for (int j = 0; j < 4; ++j) {
                const int krow = (lane & 15) + 16 * j;
                const int dlog = kk * 64 + (lane >> 4) * 16;
                bf16x8 kf = *(const bf16x8*)((const char*)sK + krow * 128 + (dlog ^ ((krow & 7) << 4)));
                sacc[j] = MFMA16(qf[kk], kf, sacc[j]);
            }
        }

        // online softmax; rows owned by this lane: (lane>>4)*4 + r
#pragma unroll
        for (int r = 0; r < 4; ++r) {
            float mx = fmaxf(fmaxf(sacc[0][r], sacc[1][r]), fmaxf(sacc[2][r], sacc[3][r])) * 0.125f;
#pragma unroll
            for (int m = 1; m < 16; m <<= 1) mx = fmaxf(mx, __shfl_xor(mx, m));
            const float mn = fmaxf(m_r[r], mx);
            const float al = __expf(m_r[r] - mn);
            m_r[r] = mn;
            float rs = 0.f;
#pragma unroll
            for (int j = 0; j < 4; ++j) {
                const float p = __expf(sacc[j][r] * 0.125f - mn);
                rs += p;
                sPw[((lane >> 4) * 4 + r) * 72 + (lane & 15) + 16 * j] = (bf16)p;
            }
            l_r[r] = l_r[r] * al + rs;   // per-lane partial sum; reduced at the end
#pragma unroll
            for (int n = 0; n < 4; ++n) oacc[n][r] *= al;
        }

        // O += P V   (A=P from sPw, B=V^T rows from sVT)
#pragma unroll
        for (int kk = 0; kk < 2; ++kk) {
            bf16x8 pa = *(const bf16x8*)&sPw[(lane & 15) * 72 + kk * 32 + (lane >> 4) * 8];
#pragma unroll
            for (int n = 0; n < 4; ++n) {
                bf16x8 vf = *(const bf16x8*)&sVT[((lane & 15) + 16 * n) * 72 + kk * 32 + (lane >> 4) * 8];
                oacc[n] = MFMA16(pa, vf, oacc[n]);
            }
        }
    }

    // finalize: reduce l across the 16-lane group, divide, store y
#pragma unroll
    for (int r = 0; r < 4; ++r) {
        float ls = l_r[r];
#pragma unroll
        for (int m = 1; m < 16; m <<= 1) ls += __shfl_xor(ls, m);
        const float inv = 1.f / ls;
        const int t = q0 + wave * 16 + (lane >> 4) * 4 + r;
#pragma unroll
        for (int n = 0; n < 4; ++n)
            y[(size_t)(b * T + t) * Cd + h * D + (lane & 15) + 16 * n] = (bf16)(oacc[n][r] * inv);
    }
}

extern "C" void kernel_launch(void* const* d_in, const int* in_sizes, int n_in,
                              void* d_out, int out_size, void* d_ws, size_t ws_size,
                              hipStream_t stream) {
    (void)in_sizes; (void)n_in; (void)out_size; (void)ws_size;
    // Inputs are fp32 (reference dtypes). Cast to bf16 in ws for MFMA compute.
    const float* x    = (const float*)d_in[0];
    const float* Wqkv = (const float*)d_in[3];
    const float* Wout = (const float*)d_in[4];
    float* out = (float*)d_out;

    bf16* xb    = (bf16*)d_ws;                       //  4096*1024
    bf16* wqkvb = xb    + (size_t)4096 * 1024;       //  3072*1024
    bf16* woutb = wqkvb + (size_t)3072 * 1024;       //  1024*1024
    bf16* qkv   = woutb + (size_t)1024 * 1024;       //  4096*3072
    bf16* yb    = qkv   + (size_t)4096 * 3072;       //  4096*1024
    // total 25,165,824 bf16 = 48 MiB

    cast_f32_bf16<<<4096 * 1024 / 2048, 256, 0, stream>>>(x, xb);
    cast_f32_bf16<<<3072 * 1024 / 2048, 256, 0, stream>>>(Wqkv, wqkvb);
    cast_f32_bf16<<<1024 * 1024 / 2048, 256, 0, stream>>>(Wout, woutb);

    // qkv = x @ W_qkv^T
    gemm_bt128<bf16><<<dim3(3072 / 128, 4096 / 128), 256, 0, stream>>>(xb, wqkvb, qkv, 4096, 3072, 1024);
    // y = attention(qkv)
    attn64<<<dim3(2048 / 64, 2 * 16), 256, 0, stream>>>(qkv, yb);
    // out = y @ W_out^T (fp32 output)
    gemm_bt128<float><<<dim3(1024 / 128, 4096 / 128), 256, 0, stream>>>(yb, woutb, out, 4096, 1024, 1024);
}

// Round 4
// 229.859 us; speedup vs baseline: 1.1011x; 1.1011x over previous
//
#include <hip/hip_runtime.h>
#include <hip/hip_bf16.h>

typedef __bf16 bf16;
typedef __attribute__((ext_vector_type(4))) __bf16 bf16x4;
typedef __attribute__((ext_vector_type(8))) __bf16 bf16x8;
typedef __attribute__((ext_vector_type(4))) float f32x4;
typedef __attribute__((ext_vector_type(16))) float f32x16;

#define MFMA16(A, B, C) __builtin_amdgcn_mfma_f32_16x16x32_bf16((A), (B), (C), 0, 0, 0)
#define MFMA32(A, B, C) __builtin_amdgcn_mfma_f32_32x32x16_bf16((A), (B), (C), 0, 0, 0)

union U8 { unsigned w[4]; bf16x8 v; };

__device__ __forceinline__ void gload_lds16(const void* g, void* l) {
    __builtin_amdgcn_global_load_lds(
        (const __attribute__((address_space(1))) void*)g,
        (__attribute__((address_space(3))) void*)l,
        16, 0, 0);
}

__device__ __forceinline__ unsigned pk2(float a, float b) {
    union { bf16 h[2]; unsigned u; } t;
    t.h[0] = (bf16)a; t.h[1] = (bf16)b;
    return t.u;
}

// 64-bit LDS transpose read (4 bf16/lane, 16-lane-group 4x16 transpose).
__device__ __forceinline__ unsigned long long tr16(unsigned addr) {
    unsigned long long r;
    asm volatile("ds_read_b64_tr_b16 %0, %1" : "=v"(r) : "v"(addr));
    return r;
}

// fp32 -> bf16 cast, 8 elements/thread, exact grid (n % 2048 == 0).
__global__ __launch_bounds__(256) void cast_f32_bf16(
    const float* __restrict__ in, bf16* __restrict__ out)
{
    const int i = (blockIdx.x * 256 + threadIdx.x) * 8;
    const float4 a = *(const float4*)(in + i);
    const float4 b = *(const float4*)(in + i + 4);
    bf16x8 o;
    o[0] = (bf16)a.x; o[1] = (bf16)a.y; o[2] = (bf16)a.z; o[3] = (bf16)a.w;
    o[4] = (bf16)b.x; o[5] = (bf16)b.y; o[6] = (bf16)b.z; o[7] = (bf16)b.w;
    *(bf16x8*)(out + i) = o;
}

// C[M,N] = A[M,K] * B[N,K]^T, bf16 inputs, fp32 accumulate, OutT output.
template <typename OutT>
__global__ __launch_bounds__(256) void gemm_bt128(
    const bf16* __restrict__ A, const bf16* __restrict__ B, OutT* __restrict__ C,
    int M, int N, int K)
{
    constexpr int BK = 32;
    __shared__ __align__(16) bf16 sA[128 * BK];
    __shared__ __align__(16) bf16 sB[128 * BK];

    const int tid  = threadIdx.x;
    const int lane = tid & 63;
    const int wave = tid >> 6;
    const int wr   = wave >> 1;
    const int wc   = wave & 1;
    const int bm   = blockIdx.y * 128;
    const int bn   = blockIdx.x * 128;

    f32x4 acc[4][4] = {};

    const size_t ldb = (size_t)K * 2;
    const int srow = wave * 32 + (lane >> 2);
    const int scol = (lane & 3) * 16;
    const char* Ab = (const char*)A + (size_t)(bm + srow) * ldb + scol;
    const char* Bb = (const char*)B + (size_t)(bn + srow) * ldb + scol;
    char* ldsA = (char*)sA + wave * 2048;
    char* ldsB = (char*)sB + wave * 2048;

    const int arow = wr * 64 + (lane & 15);
    const int brow = wc * 64 + (lane & 15);
    const int koff = (lane >> 4) * 8;

    for (int k0 = 0; k0 < K; k0 += BK) {
        __syncthreads();
        const size_t kb = (size_t)k0 * 2;
        gload_lds16(Ab + kb,            ldsA);
        gload_lds16(Ab + kb + 16 * ldb, ldsA + 1024);
        gload_lds16(Bb + kb,            ldsB);
        gload_lds16(Bb + kb + 16 * ldb, ldsB + 1024);
        __syncthreads();

        bf16x8 af[4], bfr[4];
#pragma unroll
        for (int m = 0; m < 4; ++m)
            af[m] = *(const bf16x8*)&sA[(arow + m * 16) * BK + koff];
#pragma unroll
        for (int n = 0; n < 4; ++n)
            bfr[n] = *(const bf16x8*)&sB[(brow + n * 16) * BK + koff];
#pragma unroll
        for (int m = 0; m < 4; ++m)
#pragma unroll
            for (int n = 0; n < 4; ++n)
                acc[m][n] = MFMA16(af[m], bfr[n], acc[m][n]);
    }

    const int crow0 = bm + wr * 64 + (lane >> 4) * 4;
    const int ccol0 = bn + wc * 64 + (lane & 15);
#pragma unroll
    for (int m = 0; m < 4; ++m)
#pragma unroll
        for (int n = 0; n < 4; ++n)
#pragma unroll
            for (int j = 0; j < 4; ++j)
                C[(size_t)(crow0 + m * 16 + j) * N + ccol0 + n * 16] = (OutT)acc[m][n][j];
}

// Flash attention, swapped-QK^T 32x32 structure. qkv [B*T,3072] -> y [B*T,1024].
// Grid (T/128, B*H), block 256 = 4 waves; each wave owns 32 q-rows.
__global__ __launch_bounds__(256, 2) void attn32(
    const bf16* __restrict__ qkv, bf16* __restrict__ y)
{
    constexpr int T = 2048, F = 3072, Cd = 1024;
    constexpr float c1 = 0.18033688011112042f;  // (1/8) * log2(e)

    __shared__ __align__(16) bf16 sK[64 * 64];  // row-major, XOR-swizzled rows
    __shared__ __align__(16) bf16 sV[64 * 64];  // tr-subtiled layout (see below)

    const int tid = threadIdx.x, lane = tid & 63, wave = tid >> 6;
    const int hi = lane >> 5, q5 = lane & 31;
    const int bh = blockIdx.y, b = bh >> 4, h = bh & 15;
    const bf16* qkvb = qkv + (size_t)b * T * F;
    const int qcol = h * 64, kcol = Cd + h * 64, vcol = 2 * Cd + h * 64;

    // Q fragments (B-operand of S^T mfma): qf[dsl] = Q[q5][dsl*16 + 8*hi .. +7]
    const int gq = blockIdx.x * 128 + wave * 32 + q5;
    bf16x8 qf[4];
#pragma unroll
    for (int s = 0; s < 4; ++s)
        qf[s] = *(const bf16x8*)(qkvb + (size_t)gq * F + qcol + s * 16 + hi * 8);

    // --- staging source precompute (chunk c = (wave*2+cq)*64 + lane) ---
    // K: LDS byte 16c = kv*128 + t*16, t = (d0/8) ^ (kv&7)
    const int ck0 = (wave * 2 + 0) * 64 + lane, ck1 = ck0 + 64;
    const int kvk0 = ck0 >> 3, d0k0 = ((ck0 & 7) ^ (kvk0 & 7)) << 3;
    const int kvk1 = ck1 >> 3, d0k1 = ((ck1 & 7) ^ (kvk1 & 7)) << 3;
    // V tr-subtiled: addr(kv,d) = (d&15) + (kv&3)*16 + ((d>>4)&1)*64 + ((kv>>3)&1)*128
    //                + ((kv>>2)&1)*256 + (kv>>4)*512 + (d>>5)*2048   (elements)
    const int cv0 = ck0, cv1 = ck1;
    const int kvv0 = ((cv0 >> 1) & 3) | (((cv0 >> 5) & 1) << 2) | (((cv0 >> 4) & 1) << 3) | (((cv0 >> 6) & 3) << 4);
    const int dv0  = ((cv0 & 1) << 3) | (((cv0 >> 3) & 1) << 4) | (((cv0 >> 8) & 1) << 5);
    const int kvv1 = ((cv1 >> 1) & 3) | (((cv1 >> 5) & 1) << 2) | (((cv1 >> 4) & 1) << 3) | (((cv1 >> 6) & 3) << 4);
    const int dv1  = ((cv1 & 1) << 3) | (((cv1 >> 3) & 1) << 4) | (((cv1 >> 8) & 1) << 5);

    const char* kq0 = (const char*)qkvb + (size_t)(kvk0 * F + kcol + d0k0) * 2;
    const char* kq1 = (const char*)qkvb + (size_t)(kvk1 * F + kcol + d0k1) * 2;
    const char* vq0 = (const char*)qkvb + (size_t)(kvv0 * F + vcol + dv0) * 2;
    const char* vq1 = (const char*)qkvb + (size_t)(kvv1 * F + vcol + dv1) * 2;
    char* dstK0 = (char*)sK + (wave * 2 + 0) * 1024;
    char* dstK1 = (char*)sK + (wave * 2 + 1) * 1024;
    char* dstV0 = (char*)sV + (wave * 2 + 0) * 1024;
    char* dstV1 = (char*)sV + (wave * 2 + 1) * 1024;

    const unsigned sVoff = (unsigned)(uintptr_t)(__attribute__((address_space(3))) char*)(void*)sV;
    const unsigned trb = sVoff + 8u * (unsigned)lane;   // canonical tr addressing

    const unsigned swz = (unsigned)(q5 & 7) << 4;       // K row swizzle (kv&7 == q5&7)

    f32x16 oacc[2] = {};
    float m_run = -3e38f, l_run = 0.f;

    for (int s0 = 0; s0 < T; s0 += 64) {
        __syncthreads();
        const size_t sb = (size_t)s0 * F * 2;
        gload_lds16(kq0 + sb, dstK0);
        gload_lds16(kq1 + sb, dstK1);
        gload_lds16(vq0 + sb, dstV0);
        gload_lds16(vq1 + sb, dstV1);
        __syncthreads();

        // ---- S^T[kv][q] = K · Q^T : A = K rows (kv=q5+32a), B = Q^T
        f32x16 sacc[2];
#pragma unroll
        for (int a = 0; a < 2; ++a) {
            f32x16 acc = {};
#pragma unroll
            for (int dsl = 0; dsl < 4; ++dsl) {
                const unsigned cbyte = ((unsigned)(dsl * 32 + hi * 16)) ^ swz;
                bf16x8 kf = *(const bf16x8*)((const char*)sK + (a * 32 + q5) * 128 + cbyte);
                acc = MFMA32(kf, qf[dsl], acc);
            }
            sacc[a] = acc;
        }

        // ---- online softmax (lane owns q=q5; kv = 32a + 8*(r>>2) + 4*hi + (r&3))
        float mt = -3e38f;
#pragma unroll
        for (int a = 0; a < 2; ++a)
#pragma unroll
            for (int r = 0; r < 16; ++r) mt = fmaxf(mt, sacc[a][r]);
        mt = fmaxf(mt, __shfl_xor(mt, 32));
        const float mn = fmaxf(m_run, mt);
        const float al = __builtin_exp2f((m_run - mn) * c1);
        m_run = mn;
        const float mc = mn * c1;

        float rs = 0.f;
        unsigned W[2][4][2];
#pragma unroll
        for (int a = 0; a < 2; ++a)
#pragma unroll
            for (int bb = 0; bb < 4; ++bb) {
                const float p0 = __builtin_exp2f(fmaf(sacc[a][4 * bb + 0], c1, -mc));
                const float p1 = __builtin_exp2f(fmaf(sacc[a][4 * bb + 1], c1, -mc));
                const float p2 = __builtin_exp2f(fmaf(sacc[a][4 * bb + 2], c1, -mc));
                const float p3 = __builtin_exp2f(fmaf(sacc[a][4 * bb + 3], c1, -mc));
                rs += (p0 + p1) + (p2 + p3);
                W[a][bb][0] = pk2(p0, p1);
                W[a][bb][1] = pk2(p2, p3);
            }
        l_run = fmaf(l_run, al, rs);
#pragma unroll
        for (int d = 0; d < 2; ++d)
#pragma unroll
            for (int r = 0; r < 16; ++r) oacc[d][r] *= al;

        // ---- redistribute P into PV B-fragments (xor-32 exchange of packed pairs)
        unsigned Zz[2][2][2];
#pragma unroll
        for (int a = 0; a < 2; ++a)
#pragma unroll
            for (int c = 0; c < 2; ++c)
#pragma unroll
                for (int w = 0; w < 2; ++w) {
                    const unsigned yv = hi ? W[a][2 * c][w] : W[a][2 * c + 1][w];
                    Zz[a][c][w] = (unsigned)__shfl_xor((int)yv, 32);
                }
        bf16x8 pb[4];
#pragma unroll
        for (int a = 0; a < 2; ++a)
#pragma unroll
            for (int c = 0; c < 2; ++c) {
                U8 u;
                u.w[0] = hi ? Zz[a][c][0] : W[a][2 * c][0];
                u.w[1] = hi ? Zz[a][c][1] : W[a][2 * c][1];
                u.w[2] = hi ? W[a][2 * c + 1][0] : Zz[a][c][0];
                u.w[3] = hi ? W[a][2 * c + 1][1] : Zz[a][c][1];
                pb[2 * a + c] = u.v;
            }

        // ---- O^T += V^T · P^T : A = V^T via tr reads, B = pb
        unsigned long long t0[8], t1[8];
#pragma unroll
        for (int ks = 0; ks < 4; ++ks) {
            t0[2 * ks + 0] = tr16(trb + (unsigned)(ks * 1024));
            t0[2 * ks + 1] = tr16(trb + (unsigned)(ks * 1024 + 512));
        }
#pragma unroll
        for (int ks = 0; ks < 4; ++ks) {
            t1[2 * ks + 0] = tr16(trb + (unsigned)(4096 + ks * 1024));
            t1[2 * ks + 1] = tr16(trb + (unsigned)(4096 + ks * 1024 + 512));
        }
        asm volatile("s_waitcnt lgkmcnt(8)" ::: "memory");
        __builtin_amdgcn_sched_barrier(0);
#pragma unroll
        for (int ks = 0; ks < 4; ++ks) {
            U8 u;
            u.w[0] = (unsigned)t0[2 * ks];     u.w[1] = (unsigned)(t0[2 * ks] >> 32);
            u.w[2] = (unsigned)t0[2 * ks + 1]; u.w[3] = (unsigned)(t0[2 * ks + 1] >> 32);
            oacc[0] = MFMA32(u.v, pb[ks], oacc[0]);
        }
        asm volatile("s_waitcnt lgkmcnt(0)" ::: "memory");
        __builtin_amdgcn_sched_barrier(0);
#pragma unroll
        for (int ks = 0; ks < 4; ++ks) {
            U8 u;
            u.w[0] = (unsigned)t1[2 * ks];     u.w[1] = (unsigned)(t1[2 * ks] >> 32);
            u.w[2] = (unsigned)t1[2 * ks + 1]; u.w[3] = (unsigned)(t1[2 * ks + 1] >> 32);
            oacc[1] = MFMA32(u.v, pb[ks], oacc[1]);
        }
    }

    // ---- finalize: l over both hi-halves, divide, store O[q][d] (4 bf16 / store)
    const float lt = l_run + __shfl_xor(l_run, 32);
    const float inv = 1.f / lt;
    bf16* yrow = y + (size_t)(b * T + gq) * Cd + h * 64;
#pragma unroll
    for (int d = 0; d < 2; ++d)
#pragma unroll
        for (int bb = 0; bb < 4; ++bb) {
            bf16x4 o4;
#pragma unroll
            for (int jj = 0; jj < 4; ++jj)
                o4[jj] = (bf16)(oacc[d][4 * bb + jj] * inv);
            *(bf16x4*)(yrow + d * 32 + 8 * bb + 4 * hi) = o4;
        }
}

extern "C" void kernel_launch(void* const* d_in, const int* in_sizes, int n_in,
                              void* d_out, int out_size, void* d_ws, size_t ws_size,
                              hipStream_t stream) {
    (void)in_sizes; (void)n_in; (void)out_size; (void)ws_size;
    const float* x    = (const float*)d_in[0];
    const float* Wqkv = (const float*)d_in[3];
    const float* Wout = (const float*)d_in[4];
    float* out = (float*)d_out;

    bf16* xb    = (bf16*)d_ws;                       //  4096*1024
    bf16* wqkvb = xb    + (size_t)4096 * 1024;       //  3072*1024
    bf16* woutb = wqkvb + (size_t)3072 * 1024;       //  1024*1024
    bf16* qkv   = woutb + (size_t)1024 * 1024;       //  4096*3072
    bf16* yb    = qkv   + (size_t)4096 * 3072;       //  4096*1024

    cast_f32_bf16<<<4096 * 1024 / 2048, 256, 0, stream>>>(x, xb);
    cast_f32_bf16<<<3072 * 1024 / 2048, 256, 0, stream>>>(Wqkv, wqkvb);
    cast_f32_bf16<<<1024 * 1024 / 2048, 256, 0, stream>>>(Wout, woutb);

    gemm_bt128<bf16><<<dim3(3072 / 128, 4096 / 128), 256, 0, stream>>>(xb, wqkvb, qkv, 4096, 3072, 1024);
    attn32<<<dim3(2048 / 128, 2 * 16), 256, 0, stream>>>(qkv, yb);
    gemm_bt128<float><<<dim3(1024 / 128, 4096 / 128), 256, 0, stream>>>(yb, woutb, out, 4096, 1024, 1024);
}

// Round 5
// 226.429 us; speedup vs baseline: 1.1178x; 1.0152x over previous
//
#include <hip/hip_runtime.h>
#include <hip/hip_bf16.h>

typedef __bf16 bf16;
typedef __attribute__((ext_vector_type(4))) __bf16 bf16x4;
typedef __attribute__((ext_vector_type(8))) __bf16 bf16x8;
typedef __attribute__((ext_vector_type(4))) float f32x4;
typedef __attribute__((ext_vector_type(16))) float f32x16;

#define MFMA16(A, B, C) __builtin_amdgcn_mfma_f32_16x16x32_bf16((A), (B), (C), 0, 0, 0)
#define MFMA32(A, B, C) __builtin_amdgcn_mfma_f32_32x32x16_bf16((A), (B), (C), 0, 0, 0)

union U8 { unsigned w[4]; bf16x8 v; };

__device__ __forceinline__ void gload_lds16(const void* g, void* l) {
    __builtin_amdgcn_global_load_lds(
        (const __attribute__((address_space(1))) void*)g,
        (__attribute__((address_space(3))) void*)l,
        16, 0, 0);
}

__device__ __forceinline__ unsigned pk2(float a, float b) {
    union { bf16 h[2]; unsigned u; } t;
    t.h[0] = (bf16)a; t.h[1] = (bf16)b;
    return t.u;
}

__device__ __forceinline__ unsigned long long tr16(unsigned addr) {
    unsigned long long r;
    asm volatile("ds_read_b64_tr_b16 %0, %1" : "=v"(r) : "v"(addr));
    return r;
}

// fp32 -> bf16 cast, 8 elements/thread, exact grid (n % 2048 == 0).
__global__ __launch_bounds__(256) void cast_f32_bf16(
    const float* __restrict__ in, bf16* __restrict__ out)
{
    const int i = (blockIdx.x * 256 + threadIdx.x) * 8;
    const float4 a = *(const float4*)(in + i);
    const float4 b = *(const float4*)(in + i + 4);
    bf16x8 o;
    o[0] = (bf16)a.x; o[1] = (bf16)a.y; o[2] = (bf16)a.z; o[3] = (bf16)a.w;
    o[4] = (bf16)b.x; o[5] = (bf16)b.y; o[6] = (bf16)b.z; o[7] = (bf16)b.w;
    *(bf16x8*)(out + i) = o;
}

// C[M,N] = A[M,K] * B[N,K]^T, bf16 inputs, fp32 accumulate, OutT output.
template <typename OutT>
__global__ __launch_bounds__(256) void gemm_bt128(
    const bf16* __restrict__ A, const bf16* __restrict__ B, OutT* __restrict__ C,
    int M, int N, int K)
{
    constexpr int BK = 32;
    __shared__ __align__(16) bf16 sA[128 * BK];
    __shared__ __align__(16) bf16 sB[128 * BK];

    const int tid  = threadIdx.x;
    const int lane = tid & 63;
    const int wave = tid >> 6;
    const int wr   = wave >> 1;
    const int wc   = wave & 1;
    const int bm   = blockIdx.y * 128;
    const int bn   = blockIdx.x * 128;

    f32x4 acc[4][4] = {};

    const size_t ldb = (size_t)K * 2;
    const int srow = wave * 32 + (lane >> 2);
    const int scol = (lane & 3) * 16;
    const char* Ab = (const char*)A + (size_t)(bm + srow) * ldb + scol;
    const char* Bb = (const char*)B + (size_t)(bn + srow) * ldb + scol;
    char* ldsA = (char*)sA + wave * 2048;
    char* ldsB = (char*)sB + wave * 2048;

    const int arow = wr * 64 + (lane & 15);
    const int brow = wc * 64 + (lane & 15);
    const int koff = (lane >> 4) * 8;

    for (int k0 = 0; k0 < K; k0 += BK) {
        __syncthreads();
        const size_t kb = (size_t)k0 * 2;
        gload_lds16(Ab + kb,            ldsA);
        gload_lds16(Ab + kb + 16 * ldb, ldsA + 1024);
        gload_lds16(Bb + kb,            ldsB);
        gload_lds16(Bb + kb + 16 * ldb, ldsB + 1024);
        __syncthreads();

        bf16x8 af[4], bfr[4];
#pragma unroll
        for (int m = 0; m < 4; ++m)
            af[m] = *(const bf16x8*)&sA[(arow + m * 16) * BK + koff];
#pragma unroll
        for (int n = 0; n < 4; ++n)
            bfr[n] = *(const bf16x8*)&sB[(brow + n * 16) * BK + koff];
#pragma unroll
        for (int m = 0; m < 4; ++m)
#pragma unroll
            for (int n = 0; n < 4; ++n)
                acc[m][n] = MFMA16(af[m], bfr[n], acc[m][n]);
    }

    const int crow0 = bm + wr * 64 + (lane >> 4) * 4;
    const int ccol0 = bn + wc * 64 + (lane & 15);
#pragma unroll
    for (int m = 0; m < 4; ++m)
#pragma unroll
        for (int n = 0; n < 4; ++n)
#pragma unroll
            for (int j = 0; j < 4; ++j)
                C[(size_t)(crow0 + m * 16 + j) * N + ccol0 + n * 16] = (OutT)acc[m][n][j];
}

// Flash attention, swapped-QK^T 32x32, intra-block KV-split x2.
// Grid (T/128, B*H), block 512 = 8 waves. Waves 0-3: kv [0,1024); 4-7: [1024,2048).
// Wave (grp, wq) owns q-rows [blockIdx.x*128 + wq*32, +32). LDS merge at end.
__global__ __launch_bounds__(512, 4) void attn32(
    const bf16* __restrict__ qkv, bf16* __restrict__ y)
{
    constexpr int T = 2048, F = 3072, Cd = 1024;
    constexpr float c1 = 0.18033688011112042f;  // (1/8) * log2(e)

    // union: [tiles: sK 2x8K | sV 2x8K = 32K]  /  [merge: O 4x64x36 f32 + ml 4x64x2 f32 = 38K]
    __shared__ __align__(16) char smem[38912];

    const int tid = threadIdx.x, lane = tid & 63, w = tid >> 6;
    const int wq = w & 3, grp = w >> 2;
    const int hi = lane >> 5, q5 = lane & 31;
    const int bh = blockIdx.y, b = bh >> 4, h = bh & 15;
    const bf16* qkvb = qkv + (size_t)b * T * F;
    const int qcol = h * 64, kcol = Cd + h * 64, vcol = 2 * Cd + h * 64;

    char* sKg = smem + grp * 8192;           // K tile [64][64], XOR-swizzled rows
    char* sVg = smem + 16384 + grp * 8192;   // V tile, tr-subtiled layout

    // Q fragments (B-operand of S^T mfma)
    const int gq = blockIdx.x * 128 + wq * 32 + q5;
    bf16x8 qf[4];
#pragma unroll
    for (int s = 0; s < 4; ++s)
        qf[s] = *(const bf16x8*)(qkvb + (size_t)gq * F + qcol + s * 16 + hi * 8);

    // staging source precompute (chunk c = (wq*2+cq)*64 + lane)
    const int ck0 = (wq * 2 + 0) * 64 + lane, ck1 = ck0 + 64;
    const int kvk0 = ck0 >> 3, d0k0 = ((ck0 & 7) ^ (kvk0 & 7)) << 3;
    const int kvk1 = ck1 >> 3, d0k1 = ((ck1 & 7) ^ (kvk1 & 7)) << 3;
    const int cv0 = ck0, cv1 = ck1;
    const int kvv0 = ((cv0 >> 1) & 3) | (((cv0 >> 5) & 1) << 2) | (((cv0 >> 4) & 1) << 3) | (((cv0 >> 6) & 3) << 4);
    const int dv0  = ((cv0 & 1) << 3) | (((cv0 >> 3) & 1) << 4) | (((cv0 >> 8) & 1) << 5);
    const int kvv1 = ((cv1 >> 1) & 3) | (((cv1 >> 5) & 1) << 2) | (((cv1 >> 4) & 1) << 3) | (((cv1 >> 6) & 3) << 4);
    const int dv1  = ((cv1 & 1) << 3) | (((cv1 >> 3) & 1) << 4) | (((cv1 >> 8) & 1) << 5);

    const size_t gbase = (size_t)grp * 1024 * F * 2;  // group kv offset (bytes)
    const char* kq0 = (const char*)qkvb + gbase + (size_t)(kvk0 * F + kcol + d0k0) * 2;
    const char* kq1 = (const char*)qkvb + gbase + (size_t)(kvk1 * F + kcol + d0k1) * 2;
    const char* vq0 = (const char*)qkvb + gbase + (size_t)(kvv0 * F + vcol + dv0) * 2;
    const char* vq1 = (const char*)qkvb + gbase + (size_t)(kvv1 * F + vcol + dv1) * 2;
    char* dstK0 = sKg + (wq * 2 + 0) * 1024;
    char* dstK1 = sKg + (wq * 2 + 1) * 1024;
    char* dstV0 = sVg + (wq * 2 + 0) * 1024;
    char* dstV1 = sVg + (wq * 2 + 1) * 1024;

    const unsigned sVoff = (unsigned)(uintptr_t)(__attribute__((address_space(3))) char*)(void*)sVg;
    const unsigned trb = sVoff + 8u * (unsigned)lane;
    const unsigned swz = (unsigned)(q5 & 7) << 4;

    f32x16 oacc[2] = {};
    float m_run = -3e38f, l_run = 0.f;

    for (int it = 0; it < 16; ++it) {
        __syncthreads();
        const size_t sb = (size_t)it * 64 * F * 2;
        gload_lds16(kq0 + sb, dstK0);
        gload_lds16(kq1 + sb, dstK1);
        gload_lds16(vq0 + sb, dstV0);
        gload_lds16(vq1 + sb, dstV1);
        __syncthreads();

        // ---- S^T[kv][q] = K · Q^T
        f32x16 sacc[2];
        __builtin_amdgcn_s_setprio(1);
#pragma unroll
        for (int a = 0; a < 2; ++a) {
            f32x16 acc = {};
#pragma unroll
            for (int dsl = 0; dsl < 4; ++dsl) {
                const unsigned cbyte = ((unsigned)(dsl * 32 + hi * 16)) ^ swz;
                bf16x8 kf = *(const bf16x8*)(sKg + (a * 32 + q5) * 128 + cbyte);
                acc = MFMA32(kf, qf[dsl], acc);
            }
            sacc[a] = acc;
        }
        __builtin_amdgcn_s_setprio(0);

        // ---- online softmax with defer-max (T13): skip rescale if max growth small
        float mt = -3e38f;
#pragma unroll
        for (int a = 0; a < 2; ++a)
#pragma unroll
            for (int r = 0; r < 16; ++r) mt = fmaxf(mt, sacc[a][r]);
        mt = fmaxf(mt, __shfl_xor(mt, 32));
        if (__any(mt > m_run + 64.0f)) {   // 64 raw = 11.54 in log2 domain, p <= 2981
            const float mn = fmaxf(m_run, mt);
            const float al = __builtin_exp2f((m_run - mn) * c1);
            m_run = mn;
            l_run *= al;
#pragma unroll
            for (int d = 0; d < 2; ++d)
#pragma unroll
                for (int r = 0; r < 16; ++r) oacc[d][r] *= al;
        }
        const float mc = m_run * c1;

        float rs = 0.f;
        unsigned W[2][4][2];
#pragma unroll
        for (int a = 0; a < 2; ++a)
#pragma unroll
            for (int bb = 0; bb < 4; ++bb) {
                const float p0 = __builtin_exp2f(fmaf(sacc[a][4 * bb + 0], c1, -mc));
                const float p1 = __builtin_exp2f(fmaf(sacc[a][4 * bb + 1], c1, -mc));
                const float p2 = __builtin_exp2f(fmaf(sacc[a][4 * bb + 2], c1, -mc));
                const float p3 = __builtin_exp2f(fmaf(sacc[a][4 * bb + 3], c1, -mc));
                rs += (p0 + p1) + (p2 + p3);
                W[a][bb][0] = pk2(p0, p1);
                W[a][bb][1] = pk2(p2, p3);
            }
        l_run += rs;

        // ---- redistribute P into PV B-fragments (xor-32 exchange)
        unsigned Zz[2][2][2];
#pragma unroll
        for (int a = 0; a < 2; ++a)
#pragma unroll
            for (int c = 0; c < 2; ++c)
#pragma unroll
                for (int ww = 0; ww < 2; ++ww) {
                    const unsigned yv = hi ? W[a][2 * c][ww] : W[a][2 * c + 1][ww];
                    Zz[a][c][ww] = (unsigned)__shfl_xor((int)yv, 32);
                }
        bf16x8 pb[4];
#pragma unroll
        for (int a = 0; a < 2; ++a)
#pragma unroll
            for (int c = 0; c < 2; ++c) {
                U8 u;
                u.w[0] = hi ? Zz[a][c][0] : W[a][2 * c][0];
                u.w[1] = hi ? Zz[a][c][1] : W[a][2 * c][1];
                u.w[2] = hi ? W[a][2 * c + 1][0] : Zz[a][c][0];
                u.w[3] = hi ? W[a][2 * c + 1][1] : Zz[a][c][1];
                pb[2 * a + c] = u.v;
            }

        // ---- O^T += V^T · P^T (A = V^T via tr reads)
        unsigned long long t0[8], t1[8];
#pragma unroll
        for (int ks = 0; ks < 4; ++ks) {
            t0[2 * ks + 0] = tr16(trb + (unsigned)(ks * 1024));
            t0[2 * ks + 1] = tr16(trb + (unsigned)(ks * 1024 + 512));
        }
#pragma unroll
        for (int ks = 0; ks < 4; ++ks) {
            t1[2 * ks + 0] = tr16(trb + (unsigned)(4096 + ks * 1024));
            t1[2 * ks + 1] = tr16(trb + (unsigned)(4096 + ks * 1024 + 512));
        }
        asm volatile("s_waitcnt lgkmcnt(8)" ::: "memory");
        __builtin_amdgcn_sched_barrier(0);
        __builtin_amdgcn_s_setprio(1);
#pragma unroll
        for (int ks = 0; ks < 4; ++ks) {
            U8 u;
            u.w[0] = (unsigned)t0[2 * ks];     u.w[1] = (unsigned)(t0[2 * ks] >> 32);
            u.w[2] = (unsigned)t0[2 * ks + 1]; u.w[3] = (unsigned)(t0[2 * ks + 1] >> 32);
            oacc[0] = MFMA32(u.v, pb[ks], oacc[0]);
        }
        __builtin_amdgcn_s_setprio(0);
        asm volatile("s_waitcnt lgkmcnt(0)" ::: "memory");
        __builtin_amdgcn_sched_barrier(0);
        __builtin_amdgcn_s_setprio(1);
#pragma unroll
        for (int ks = 0; ks < 4; ++ks) {
            U8 u;
            u.w[0] = (unsigned)t1[2 * ks];     u.w[1] = (unsigned)(t1[2 * ks] >> 32);
            u.w[2] = (unsigned)t1[2 * ks + 1]; u.w[3] = (unsigned)(t1[2 * ks + 1] >> 32);
            oacc[1] = MFMA32(u.v, pb[ks], oacc[1]);
        }
        __builtin_amdgcn_s_setprio(0);
    }

    // ---- merge the two kv-halves via LDS (union with tile buffers)
    __syncthreads();   // tiles dead; safe to alias
    float* Obuf  = (float*)smem;                     // [4][64][36]
    float* mlbuf = (float*)(smem + 36864);           // [4][64][2]
    if (grp == 1) {
        float* po = Obuf + (wq * 64 + lane) * 36;
#pragma unroll
        for (int d5 = 0; d5 < 2; ++d5)
#pragma unroll
            for (int j = 0; j < 4; ++j) {
                f32x4 t;
                t[0] = oacc[d5][4 * j + 0]; t[1] = oacc[d5][4 * j + 1];
                t[2] = oacc[d5][4 * j + 2]; t[3] = oacc[d5][4 * j + 3];
                *(f32x4*)(po + d5 * 16 + 4 * j) = t;
            }
        mlbuf[(wq * 64 + lane) * 2 + 0] = m_run;
        mlbuf[(wq * 64 + lane) * 2 + 1] = l_run;
    }
    __syncthreads();
    if (grp == 0) {
        const float mB = mlbuf[(wq * 64 + lane) * 2 + 0];
        const float lB = mlbuf[(wq * 64 + lane) * 2 + 1];
        const float m  = fmaxf(m_run, mB);
        const float fA = __builtin_exp2f((m_run - m) * c1);
        const float fB = __builtin_exp2f((mB - m) * c1);
        const float lh = l_run * fA + lB * fB;
        const float lt = lh + __shfl_xor(lh, 32);
        const float inv = 1.f / lt;
        const float* po = Obuf + (wq * 64 + lane) * 36;
        bf16* yrow = y + (size_t)(b * T + gq) * Cd + h * 64;
#pragma unroll
        for (int d5 = 0; d5 < 2; ++d5)
#pragma unroll
            for (int bb = 0; bb < 4; ++bb) {
                const f32x4 ob = *(const f32x4*)(po + d5 * 16 + 4 * bb);
                bf16x4 o4;
#pragma unroll
                for (int jj = 0; jj < 4; ++jj)
                    o4[jj] = (bf16)((oacc[d5][4 * bb + jj] * fA + ob[jj] * fB) * inv);
                *(bf16x4*)(yrow + d5 * 32 + 8 * bb + 4 * hi) = o4;
            }
    }
}

extern "C" void kernel_launch(void* const* d_in, const int* in_sizes, int n_in,
                              void* d_out, int out_size, void* d_ws, size_t ws_size,
                              hipStream_t stream) {
    (void)in_sizes; (void)n_in; (void)out_size; (void)ws_size;
    const float* x    = (const float*)d_in[0];
    const float* Wqkv = (const float*)d_in[3];
    const float* Wout = (const float*)d_in[4];
    float* out = (float*)d_out;

    bf16* xb    = (bf16*)d_ws;                       //  4096*1024
    bf16* wqkvb = xb    + (size_t)4096 * 1024;       //  3072*1024
    bf16* woutb = wqkvb + (size_t)3072 * 1024;       //  1024*1024
    bf16* qkv   = woutb + (size_t)1024 * 1024;       //  4096*3072
    bf16* yb    = qkv   + (size_t)4096 * 3072;       //  4096*1024

    cast_f32_bf16<<<4096 * 1024 / 2048, 256, 0, stream>>>(x, xb);
    cast_f32_bf16<<<3072 * 1024 / 2048, 256, 0, stream>>>(Wqkv, wqkvb);
    cast_f32_bf16<<<1024 * 1024 / 2048, 256, 0, stream>>>(Wout, woutb);

    gemm_bt128<bf16><<<dim3(3072 / 128, 4096 / 128), 256, 0, stream>>>(xb, wqkvb, qkv, 4096, 3072, 1024);
    attn32<<<dim3(2048 / 128, 2 * 16), 512, 0, stream>>>(qkv, yb);
    gemm_bt128<float><<<dim3(1024 / 128, 4096 / 128), 256, 0, stream>>>(yb, woutb, out, 4096, 1024, 1024);
}

// Round 7
// 208.965 us; speedup vs baseline: 1.2112x; 1.0836x over previous
//
#include <hip/hip_runtime.h>
#include <hip/hip_bf16.h>

typedef __bf16 bf16;
typedef __attribute__((ext_vector_type(4))) __bf16 bf16x4;
typedef __attribute__((ext_vector_type(8))) __bf16 bf16x8;
typedef __attribute__((ext_vector_type(4))) float f32x4;
typedef __attribute__((ext_vector_type(16))) float f32x16;

#define MFMA16(A, B, C) __builtin_amdgcn_mfma_f32_16x16x32_bf16((A), (B), (C), 0, 0, 0)
#define MFMA32(A, B, C) __builtin_amdgcn_mfma_f32_32x32x16_bf16((A), (B), (C), 0, 0, 0)

union U8 { unsigned w[4]; bf16x8 v; };

__device__ __forceinline__ void gload_lds16(const void* g, void* l) {
    __builtin_amdgcn_global_load_lds(
        (const __attribute__((address_space(1))) void*)g,
        (__attribute__((address_space(3))) void*)l,
        16, 0, 0);
}

__device__ __forceinline__ unsigned pk2(float a, float b) {
    union { bf16 h[2]; unsigned u; } t;
    t.h[0] = (bf16)a; t.h[1] = (bf16)b;
    return t.u;
}

__device__ __forceinline__ unsigned long long tr16(unsigned addr) {
    unsigned long long r;
    asm volatile("ds_read_b64_tr_b16 %0, %1" : "=v"(r) : "v"(addr));
    return r;
}

// Fused fp32->bf16 cast of x | W_qkv | W_out into contiguous ws region.
// 8 elems/thread; region boundaries are multiples of 8*256 so branches are block-uniform.
__global__ __launch_bounds__(256) void cast3_f32_bf16(
    const float* __restrict__ x, const float* __restrict__ wq,
    const float* __restrict__ wo, bf16* __restrict__ out)
{
    const int i = (blockIdx.x * 256 + threadIdx.x) * 8;
    const float* src;
    int off;
    if (i < 4194304)      { src = x;  off = i; }
    else if (i < 7340032) { src = wq; off = i - 4194304; }
    else                  { src = wo; off = i - 7340032; }
    const float4 a = *(const float4*)(src + off);
    const float4 b = *(const float4*)(src + off + 4);
    bf16x8 o;
    o[0] = (bf16)a.x; o[1] = (bf16)a.y; o[2] = (bf16)a.z; o[3] = (bf16)a.w;
    o[4] = (bf16)b.x; o[5] = (bf16)b.y; o[6] = (bf16)b.z; o[7] = (bf16)b.w;
    *(bf16x8*)(out + i) = o;
}

// C[M,N] = A[M,K] * B[N,K]^T, bf16 in, fp32 accum, OutT out. BM=128, BN in {128,64}.
template <typename OutT, int BN>
__global__ __launch_bounds__(256) void gemm_bt(
    const bf16* __restrict__ A, const bf16* __restrict__ B, OutT* __restrict__ C,
    int M, int N, int K)
{
    constexpr int BK = 32;
    constexpr int NF = BN / 32;            // B-frags per wave (col dir)
    __shared__ __align__(16) bf16 sA[128 * BK];
    __shared__ __align__(16) bf16 sB[BN * BK];

    const int tid  = threadIdx.x;
    const int lane = tid & 63;
    const int wave = tid >> 6;
    const int wr   = wave >> 1;
    const int wc   = wave & 1;
    const int bm   = blockIdx.y * 128;
    const int bn   = blockIdx.x * BN;

    f32x4 acc[4][NF] = {};

    const size_t ldb = (size_t)K * 2;
    const int srowA = wave * 32 + (lane >> 2);
    const int scolA = (lane & 3) * 16;
    const char* Ab = (const char*)A + (size_t)(bm + srowA) * ldb + scolA;
    char* ldsA = (char*)sA + wave * 2048;

    const char* Bb;
    char* ldsB;
    if constexpr (BN == 128) {
        Bb   = (const char*)B + (size_t)(bn + srowA) * ldb + scolA;
        ldsB = (char*)sB + wave * 2048;
    } else {
        Bb   = (const char*)B + (size_t)(bn + (tid >> 2)) * ldb + (tid & 3) * 16;
        ldsB = (char*)sB + tid * 16;
    }

    const int arow = wr * 64 + (lane & 15);
    const int brow = wc * (BN / 2) + (lane & 15);
    const int koff = (lane >> 4) * 8;

    for (int k0 = 0; k0 < K; k0 += BK) {
        __syncthreads();
        const size_t kb = (size_t)k0 * 2;
        gload_lds16(Ab + kb,            ldsA);
        gload_lds16(Ab + kb + 16 * ldb, ldsA + 1024);
        if constexpr (BN == 128) {
            gload_lds16(Bb + kb,            ldsB);
            gload_lds16(Bb + kb + 16 * ldb, ldsB + 1024);
        } else {
            gload_lds16(Bb + kb, ldsB);
        }
        __syncthreads();

        bf16x8 af[4], bfr[NF];
#pragma unroll
        for (int m = 0; m < 4; ++m)
            af[m] = *(const bf16x8*)&sA[(arow + m * 16) * BK + koff];
#pragma unroll
        for (int n = 0; n < NF; ++n)
            bfr[n] = *(const bf16x8*)&sB[(brow + n * 16) * BK + koff];
#pragma unroll
        for (int m = 0; m < 4; ++m)
#pragma unroll
            for (int n = 0; n < NF; ++n)
                acc[m][n] = MFMA16(af[m], bfr[n], acc[m][n]);
    }

    const int crow0 = bm + wr * 64 + (lane >> 4) * 4;
    const int ccol0 = bn + wc * (BN / 2) + (lane & 15);
#pragma unroll
    for (int m = 0; m < 4; ++m)
#pragma unroll
        for (int n = 0; n < NF; ++n)
#pragma unroll
            for (int j = 0; j < 4; ++j)
                C[(size_t)(crow0 + m * 16 + j) * N + ccol0 + n * 16] = (OutT)acc[m][n][j];
}

// Flash attention, swapped-QK^T 32x32, intra-block KV-split x2, K/V double-buffered.
// Grid (T/128, B*H), block 512 = 8 waves. Waves 0-3: kv [0,1024); 4-7: [1024,2048).
__global__ __launch_bounds__(512, 4) void attn32(
    const bf16* __restrict__ qkv, bf16* __restrict__ y)
{
    constexpr int T = 2048, F = 3072, Cd = 1024;
    constexpr float c1 = 0.18033688011112042f;  // (1/8) * log2(e)

    // [tiles: per grp {K[2][8K] V[2][8K]} = 32K, x2 grp = 64K] / [merge: 38912 B] union
    __shared__ __align__(16) char smem[65536];

    const int tid = threadIdx.x, lane = tid & 63, w = tid >> 6;
    const int wq = w & 3, grp = w >> 2;
    const int hi = lane >> 5, q5 = lane & 31;
    const int bh = blockIdx.y, b = bh >> 4, h = bh & 15;
    const bf16* qkvb = qkv + (size_t)b * T * F;
    const int qcol = h * 64, kcol = Cd + h * 64, vcol = 2 * Cd + h * 64;

    const int grpbase = grp * 32768;   // K bufs at +0/+8192, V bufs at +16384/+24576

    // Q fragments (B-operand of S^T mfma)
    const int gq = blockIdx.x * 128 + wq * 32 + q5;
    bf16x8 qf[4];
#pragma unroll
    for (int s = 0; s < 4; ++s)
        qf[s] = *(const bf16x8*)(qkvb + (size_t)gq * F + qcol + s * 16 + hi * 8);

    // staging source precompute (chunk c = (wq*2+cq)*64 + lane)
    const int ck0 = (wq * 2 + 0) * 64 + lane, ck1 = ck0 + 64;
    const int kvk0 = ck0 >> 3, d0k0 = ((ck0 & 7) ^ (kvk0 & 7)) << 3;
    const int kvk1 = ck1 >> 3, d0k1 = ((ck1 & 7) ^ (kvk1 & 7)) << 3;
    const int cv0 = ck0, cv1 = ck1;
    const int kvv0 = ((cv0 >> 1) & 3) | (((cv0 >> 5) & 1) << 2) | (((cv0 >> 4) & 1) << 3) | (((cv0 >> 6) & 3) << 4);
    const int dv0  = ((cv0 & 1) << 3) | (((cv0 >> 3) & 1) << 4) | (((cv0 >> 8) & 1) << 5);
    const int kvv1 = ((cv1 >> 1) & 3) | (((cv1 >> 5) & 1) << 2) | (((cv1 >> 4) & 1) << 3) | (((cv1 >> 6) & 3) << 4);
    const int dv1  = ((cv1 & 1) << 3) | (((cv1 >> 3) & 1) << 4) | (((cv1 >> 8) & 1) << 5);

    const size_t gbase = (size_t)grp * 1024 * F * 2;
    const char* kq0 = (const char*)qkvb + gbase + (size_t)(kvk0 * F + kcol + d0k0) * 2;
    const char* kq1 = (const char*)qkvb + gbase + (size_t)(kvk1 * F + kcol + d0k1) * 2;
    const char* vq0 = (const char*)qkvb + gbase + (size_t)(kvv0 * F + vcol + dv0) * 2;
    const char* vq1 = (const char*)qkvb + gbase + (size_t)(kvv1 * F + vcol + dv1) * 2;

    const unsigned smemAddr = (unsigned)(uintptr_t)(__attribute__((address_space(3))) char*)(void*)smem;
    const unsigned trb0 = smemAddr + grpbase + 16384u + 8u * (unsigned)lane;
    const unsigned swz = (unsigned)(q5 & 7) << 4;

    f32x16 oacc[2] = {};
    float m_run = -3e38f, l_run = 0.f;

    // prologue: stage tile 0 into buf 0
    {
        char* kb = smem + grpbase;
        char* vb = smem + grpbase + 16384;
        gload_lds16(kq0, kb + (wq * 2 + 0) * 1024);
        gload_lds16(kq1, kb + (wq * 2 + 1) * 1024);
        gload_lds16(vq0, vb + (wq * 2 + 0) * 1024);
        gload_lds16(vq1, vb + (wq * 2 + 1) * 1024);
    }

    int cur = 0;
    for (int it = 0; it < 16; ++it) {
        __syncthreads();   // drains vmcnt(0): stage(buf cur) complete; buf cur^1 free

        if (it < 15) {     // issue next-tile stage; latency hides under compute below
            const size_t sb = (size_t)(it + 1) * 64 * F * 2;
            char* kb = smem + grpbase + ((cur ^ 1) << 13);
            char* vb = smem + grpbase + 16384 + ((cur ^ 1) << 13);
            gload_lds16(kq0 + sb, kb + (wq * 2 + 0) * 1024);
            gload_lds16(kq1 + sb, kb + (wq * 2 + 1) * 1024);
            gload_lds16(vq0 + sb, vb + (wq * 2 + 0) * 1024);
            gload_lds16(vq1 + sb, vb + (wq * 2 + 1) * 1024);
        }

        const char* sKc = smem + grpbase + (cur << 13);
        const unsigned trbc = trb0 + (unsigned)(cur << 13);

        // ---- S^T[kv][q] = K · Q^T
        f32x16 sacc[2];
        __builtin_amdgcn_s_setprio(1);
#pragma unroll
        for (int a = 0; a < 2; ++a) {
            f32x16 acc = {};
#pragma unroll
            for (int dsl = 0; dsl < 4; ++dsl) {
                const unsigned cbyte = ((unsigned)(dsl * 32 + hi * 16)) ^ swz;
                bf16x8 kf = *(const bf16x8*)(sKc + (a * 32 + q5) * 128 + cbyte);
                acc = MFMA32(kf, qf[dsl], acc);
            }
            sacc[a] = acc;
        }
        __builtin_amdgcn_s_setprio(0);

        // ---- online softmax with defer-max (T13)
        float mt = -3e38f;
#pragma unroll
        for (int a = 0; a < 2; ++a)
#pragma unroll
            for (int r = 0; r < 16; ++r) mt = fmaxf(mt, sacc[a][r]);
        mt = fmaxf(mt, __shfl_xor(mt, 32));
        if (__any(mt > m_run + 64.0f)) {
            const float mn = fmaxf(m_run, mt);
            const float al = __builtin_exp2f((m_run - mn) * c1);
            m_run = mn;
            l_run *= al;
#pragma unroll
            for (int d = 0; d < 2; ++d)
#pragma unroll
                for (int r = 0; r < 16; ++r) oacc[d][r] *= al;
        }
        const float mc = m_run * c1;

        float rs = 0.f;
        unsigned W[2][4][2];
#pragma unroll
        for (int a = 0; a < 2; ++a)
#pragma unroll
            for (int bb = 0; bb < 4; ++bb) {
                const float p0 = __builtin_exp2f(fmaf(sacc[a][4 * bb + 0], c1, -mc));
                const float p1 = __builtin_exp2f(fmaf(sacc[a][4 * bb + 1], c1, -mc));
                const float p2 = __builtin_exp2f(fmaf(sacc[a][4 * bb + 2], c1, -mc));
                const float p3 = __builtin_exp2f(fmaf(sacc[a][4 * bb + 3], c1, -mc));
                rs += (p0 + p1) + (p2 + p3);
                W[a][bb][0] = pk2(p0, p1);
                W[a][bb][1] = pk2(p2, p3);
            }
        l_run += rs;

        // ---- redistribute P into PV B-fragments (xor-32 exchange)
        unsigned Zz[2][2][2];
#pragma unroll
        for (int a = 0; a < 2; ++a)
#pragma unroll
            for (int c = 0; c < 2; ++c)
#pragma unroll
                for (int ww = 0; ww < 2; ++ww) {
                    const unsigned yv = hi ? W[a][2 * c][ww] : W[a][2 * c + 1][ww];
                    Zz[a][c][ww] = (unsigned)__shfl_xor((int)yv, 32);
                }
        bf16x8 pb[4];
#pragma unroll
        for (int a = 0; a < 2; ++a)
#pragma unroll
            for (int c = 0; c < 2; ++c) {
                U8 u;
                u.w[0] = hi ? Zz[a][c][0] : W[a][2 * c][0];
                u.w[1] = hi ? Zz[a][c][1] : W[a][2 * c][1];
                u.w[2] = hi ? W[a][2 * c + 1][0] : Zz[a][c][0];
                u.w[3] = hi ? W[a][2 * c + 1][1] : Zz[a][c][1];
                pb[2 * a + c] = u.v;
            }

        // ---- O^T += V^T · P^T (A = V^T via tr reads)
        unsigned long long t0[8], t1[8];
#pragma unroll
        for (int ks = 0; ks < 4; ++ks) {
            t0[2 * ks + 0] = tr16(trbc + (unsigned)(ks * 1024));
            t0[2 * ks + 1] = tr16(trbc + (unsigned)(ks * 1024 + 512));
        }
#pragma unroll
        for (int ks = 0; ks < 4; ++ks) {
            t1[2 * ks + 0] = tr16(trbc + (unsigned)(4096 + ks * 1024));
            t1[2 * ks + 1] = tr16(trbc + (unsigned)(4096 + ks * 1024 + 512));
        }
        asm volatile("s_waitcnt lgkmcnt(8)" ::: "memory");
        __builtin_amdgcn_sched_barrier(0);
        __builtin_amdgcn_s_setprio(1);
#pragma unroll
        for (int ks = 0; ks < 4; ++ks) {
            U8 u;
            u.w[0] = (unsigned)t0[2 * ks];     u.w[1] = (unsigned)(t0[2 * ks] >> 32);
            u.w[2] = (unsigned)t0[2 * ks + 1]; u.w[3] = (unsigned)(t0[2 * ks + 1] >> 32);
            oacc[0] = MFMA32(u.v, pb[ks], oacc[0]);
        }
        __builtin_amdgcn_s_setprio(0);
        asm volatile("s_waitcnt lgkmcnt(0)" ::: "memory");
        __builtin_amdgcn_sched_barrier(0);
        __builtin_amdgcn_s_setprio(1);
#pragma unroll
        for (int ks = 0; ks < 4; ++ks) {
            U8 u;
            u.w[0] = (unsigned)t1[2 * ks];     u.w[1] = (unsigned)(t1[2 * ks] >> 32);
            u.w[2] = (unsigned)t1[2 * ks + 1]; u.w[3] = (unsigned)(t1[2 * ks + 1] >> 32);
            oacc[1] = MFMA32(u.v, pb[ks], oacc[1]);
        }
        __builtin_amdgcn_s_setprio(0);

        cur ^= 1;
    }

    // ---- merge the two kv-halves via LDS (aliases tile buffers; all reads done)
    __syncthreads();
    float* Obuf  = (float*)smem;                     // [4][64][36]
    float* mlbuf = (float*)(smem + 36864);           // [4][64][2]
    if (grp == 1) {
        float* po = Obuf + (wq * 64 + lane) * 36;
#pragma unroll
        for (int d5 = 0; d5 < 2; ++d5)
#pragma unroll
            for (int j = 0; j < 4; ++j) {
                f32x4 t;
                t[0] = oacc[d5][4 * j + 0]; t[1] = oacc[d5][4 * j + 1];
                t[2] = oacc[d5][4 * j + 2]; t[3] = oacc[d5][4 * j + 3];
                *(f32x4*)(po + d5 * 16 + 4 * j) = t;
            }
        mlbuf[(wq * 64 + lane) * 2 + 0] = m_run;
        mlbuf[(wq * 64 + lane) * 2 + 1] = l_run;
    }
    __syncthreads();
    if (grp == 0) {
        const float mB = mlbuf[(wq * 64 + lane) * 2 + 0];
        const float lB = mlbuf[(wq * 64 + lane) * 2 + 1];
        const float m  = fmaxf(m_run, mB);
        const float fA = __builtin_exp2f((m_run - m) * c1);
        const float fB = __builtin_exp2f((mB - m) * c1);
        const float lh = l_run * fA + lB * fB;
        const float lt = lh + __shfl_xor(lh, 32);
        const float inv = 1.f / lt;
        const float* po = Obuf + (wq * 64 + lane) * 36;
        bf16* yrow = y + (size_t)(b * T + gq) * Cd + h * 64;
#pragma unroll
        for (int d5 = 0; d5 < 2; ++d5)
#pragma unroll
            for (int bb = 0; bb < 4; ++bb) {
                const f32x4 ob = *(const f32x4*)(po + d5 * 16 + 4 * bb);
                bf16x4 o4;
#pragma unroll
                for (int jj = 0; jj < 4; ++jj)
                    o4[jj] = (bf16)((oacc[d5][4 * bb + jj] * fA + ob[jj] * fB) * inv);
                *(bf16x4*)(yrow + d5 * 32 + 8 * bb + 4 * hi) = o4;
            }
    }
}

extern "C" void kernel_launch(void* const* d_in, const int* in_sizes, int n_in,
                              void* d_out, int out_size, void* d_ws, size_t ws_size,
                              hipStream_t stream) {
    (void)in_sizes; (void)n_in; (void)out_size; (void)ws_size;
    const float* x    = (const float*)d_in[0];
    const float* Wqkv = (const float*)d_in[3];
    const float* Wout = (const float*)d_in[4];
    float* out = (float*)d_out;

    bf16* xb    = (bf16*)d_ws;                       //  4096*1024
    bf16* wqkvb = xb    + (size_t)4096 * 1024;       //  3072*1024
    bf16* woutb = wqkvb + (size_t)3072 * 1024;       //  1024*1024
    bf16* qkv   = woutb + (size_t)1024 * 1024;       //  4096*3072
    bf16* yb    = qkv   + (size_t)4096 * 3072;       //  4096*1024

    // fused cast: x | W_qkv | W_out -> contiguous bf16 region at xb
    cast3_f32_bf16<<<8388608 / 2048, 256, 0, stream>>>(x, Wqkv, Wout, xb);

    gemm_bt<bf16, 128><<<dim3(3072 / 128, 4096 / 128), 256, 0, stream>>>(xb, wqkvb, qkv, 4096, 3072, 1024);
    attn32<<<dim3(2048 / 128, 2 * 16), 512, 0, stream>>>(qkv, yb);
    gemm_bt<float, 64><<<dim3(1024 / 64, 4096 / 128), 256, 0, stream>>>(yb, woutb, out, 4096, 1024, 1024);
}